// Round 11
// baseline (366.866 us; speedup 1.0000x reference)
//
#include <hip/hip_runtime.h>

// ---------------------------------------------------------------------------
// VectorQuantizer: N=16384 points x K=8192 codes x D=512 fp32.
// R18: R17 (330.9us) with the score tile widened 128x128 -> 128x256 at
// 256 threads, __launch_bounds__(256,2). Same verified 2-barrier loop,
// same comparator/fold/merge; mechanical changes only: wnb=(w&1)*128,
// ni 0..7 (acc[4][8] = 128 AGPR), nt 0..1 (kbase=nsplit*512+nt*256),
// 8 B staging units (Bs 256x64 = 32KB), cn[8]. Mechanism: fixed per-kt
// barrier/drain amortized over 2x MFMA; A-tile staged 2x not 4x.
// LDS ceiling moves 41% -> ~55% MfmaUtil. Falsifier: VGPR<=90 +
// WRITE_SIZE>10MB => 256-thr spill clamp too; revert next round.
// prep/gather/finalize = R17 verbatim (passed, absmax 4.9e-4).
// Dead ends: 512-thr 8-phase (R8-R11 spill clamp), stage-ahead (R14).
// Fallback (small ws): round-1 pure-fp32 VALU kernel (known-correct).
// ---------------------------------------------------------------------------

#define N_PTS   16384
#define DIM     512
#define K_CODES 8192
#define KB      512                   // screening K (hi only)
#define NSPLIT  16                    // code splits (512 codes each)
#define OUT0_N  (N_PTS * DIM)
#define NELEM_F (8388608.0f)
#define MARGIN  1.5e-2f

typedef _Float16 half8 __attribute__((ext_vector_type(8)));
typedef _Float16 f16x4 __attribute__((ext_vector_type(4)));
typedef float    f32x4 __attribute__((ext_vector_type(4)));

// fast-path workspace layout (bytes)
#define SZ_A3    (16384UL * 512 * 2)               // 16.8 MB
#define SZ_B3    (8192UL * 512 * 2)                // 8.4 MB
#define OFF_A3   0UL
#define OFF_B3   (OFF_A3 + SZ_A3)
#define OFF_CN   (OFF_B3 + SZ_B3)                  // cnorm 32 KB
#define OFF_PV1  (OFF_CN + 32768UL)
#define SZ_P     (16UL * 16384 * 4)                // 1 MB each
#define OFF_PI1  (OFF_PV1 + SZ_P)
#define OFF_PV2  (OFF_PI1 + SZ_P)
#define OFF_PI2  (OFF_PV2 + SZ_P)
#define OFF_PSUM (OFF_PI2 + SZ_P)                  // psums 64 KB (|z|^2 -> loss)
#define OFF_CNT  (OFF_PSUM + 65536UL)              // counts 32 KB
#define WS_NEED  (OFF_CNT + 32768UL)

#define GLOAD_LDS16(g, l) \
    __builtin_amdgcn_global_load_lds( \
        (const __attribute__((address_space(1))) unsigned int*)(g), \
        (__attribute__((address_space(3))) unsigned int*)(l), 16, 0, 0)

// ---------------------------------------------------------------- prep (fused)
// R17 version (verified): wave-per-row for z_e (cast + |z|^2 -> psums) and
// cb (cast + cnorm); counts zeroed grid-stride. 1024 blocks x 256 threads.
__global__ __launch_bounds__(256) void prep_all(const float* __restrict__ z_e,
                                                const float* __restrict__ cb,
                                                _Float16* __restrict__ A3,
                                                _Float16* __restrict__ B3,
                                                float* __restrict__ cnorm,
                                                unsigned int* __restrict__ counts,
                                                float* __restrict__ psums) {
    const int tid   = threadIdx.x;
    const int gid0  = blockIdx.x * 256 + tid;
    const int gsize = gridDim.x * 256;

    for (int i = gid0; i < K_CODES; i += gsize) counts[i] = 0u;

    const int lane   = tid & 63;
    const int wave   = gid0 >> 6;                  // global wave id
    const int nwaves = gsize >> 6;

    for (int r = wave; r < N_PTS; r += nwaves) {
        const float* src = z_e + (size_t)r * DIM + lane * 8;
        const float4 v0 = *(const float4*)(src);
        const float4 v1 = *(const float4*)(src + 4);
        f16x4 h0, h1;
        h0[0] = (_Float16)v0.x; h0[1] = (_Float16)v0.y;
        h0[2] = (_Float16)v0.z; h0[3] = (_Float16)v0.w;
        h1[0] = (_Float16)v1.x; h1[1] = (_Float16)v1.y;
        h1[2] = (_Float16)v1.z; h1[3] = (_Float16)v1.w;
        _Float16* dst = A3 + (size_t)r * 512 + lane * 8;
        *(f16x4*)(dst)     = h0;
        *(f16x4*)(dst + 4) = h1;
        float s = v0.x * v0.x + v0.y * v0.y + v0.z * v0.z + v0.w * v0.w
                + v1.x * v1.x + v1.y * v1.y + v1.z * v1.z + v1.w * v1.w;
#pragma unroll
        for (int o = 32; o > 0; o >>= 1) s += __shfl_down(s, o, 64);
        if (lane == 0) psums[r] = s;               // |z_r|^2 (consumed by gather)
    }

    for (int r = wave; r < K_CODES; r += nwaves) {
        const float* src = cb + (size_t)r * DIM + lane * 8;
        const float4 v0 = *(const float4*)(src);
        const float4 v1 = *(const float4*)(src + 4);
        f16x4 h0, h1;
        h0[0] = (_Float16)v0.x; h0[1] = (_Float16)v0.y;
        h0[2] = (_Float16)v0.z; h0[3] = (_Float16)v0.w;
        h1[0] = (_Float16)v1.x; h1[1] = (_Float16)v1.y;
        h1[2] = (_Float16)v1.z; h1[3] = (_Float16)v1.w;
        _Float16* dst = B3 + (size_t)r * 512 + lane * 8;
        *(f16x4*)(dst)     = h0;
        *(f16x4*)(dst + 4) = h1;
        float s = v0.x * v0.x + v0.y * v0.y + v0.z * v0.z + v0.w * v0.w
                + v1.x * v1.x + v1.y * v1.y + v1.z * v1.z + v1.w * v1.w;
#pragma unroll
        for (int o = 32; o > 0; o >>= 1) s += __shfl_down(s, o, 64);
        if (lane == 0) cnorm[r] = s;
    }
}

// ---------------------------------------------------------------- cnorm (fallback)
__global__ __launch_bounds__(128) void cnorm_kernel(const float* __restrict__ cb,
                                                    float* __restrict__ cnorm) {
    const int k = blockIdx.x;
    const int t = threadIdx.x;
    const float4 v = *(const float4*)(cb + (size_t)k * DIM + t * 4);
    float s = v.x * v.x + v.y * v.y + v.z * v.z + v.w * v.w;
#pragma unroll
    for (int o = 32; o > 0; o >>= 1) s += __shfl_down(s, o, 64);
    __shared__ float red[2];
    if ((t & 63) == 0) red[t >> 6] = s;
    __syncthreads();
    if (t == 0) cnorm[k] = red[0] + red[1];
}

// ---------------------------------------------------------------- score GEMM
// R18: 128x256 tile, BK=64, 256 threads = 4 waves (2M x 2N), wave tile
// 64x128 via 4x8 of 16x16x32 f16 MFMA (acc[4][8] = 128 AGPR). Same
// verified 2-barrier loop and XOR swizzle. Block covers its 512-code
// split in 2 passes of 256 codes. As 128x64 (16KB) + Bs 256x64 (32KB).
__global__ __launch_bounds__(256, 2) void score_kernel(
    const _Float16* __restrict__ A3, const _Float16* __restrict__ B3,
    const float* __restrict__ cnorm,
    float* __restrict__ pv1, int* __restrict__ pi1,
    float* __restrict__ pv2, int* __restrict__ pi2) {
    __shared__ _Float16 As[128 * 64];   // 16 KB
    __shared__ _Float16 Bs[256 * 64];   // 32 KB
    __shared__ float mv1[128][2], mv2[128][2];
    __shared__ int   mj1[128][2], mj2[128][2];

    const int tid = threadIdx.x;
    const int w = tid >> 6;             // wave 0..3
    const int l = tid & 63;
    const int pbase = blockIdx.x * 128;
    const int nsplit = blockIdx.y;      // 0..15
    const int wmb = (w >> 1) * 64;      // wave m offset (0/64)
    const int wnb = (w & 1) * 128;      // wave n offset (0/128)
    const int srow = w * 8 + (l >> 3);  // staging row (+ it*32)
    const int scolh = (((l & 7) ^ ((l >> 3) & 7)) * 8);   // swizzled src col

    const _Float16* aB[4];
    const _Float16* bR[8];
#pragma unroll
    for (int it = 0; it < 4; ++it)
        aB[it] = A3 + (long)(pbase + it * 32 + srow) * 512 + scolh;
#pragma unroll
    for (int it = 0; it < 8; ++it)
        bR[it] = B3 + (long)(it * 32 + srow) * 512 + scolh;

    const int q = l >> 4, x7 = l & 7, m16 = l & 15;
    const int koff0 = ((q ^ x7) * 8);          // ks=0 chunk offset (halves)
    const int rowAf = (wmb + m16) * 64;        // + mi*1024
    const int rowBf = (wnb + m16) * 64;        // + ni*1024

    float v1[16], v2[16];
    int i12[16];                               // (i1<<16) | i2, codes < 8192
#pragma unroll
    for (int s = 0; s < 16; ++s) { v1[s] = 3.0e38f; v2[s] = 3.0e38f; i12[s] = 0; }

#pragma unroll 1
    for (int nt = 0; nt < 2; ++nt) {
        const int kbase = nsplit * 512 + nt * 256;   // code row base
        const long bOff = (long)kbase * 512;
        // hoisted cnorm loads: issue now, consumed at the fold (8 kt of cover)
        float cn[8];
#pragma unroll
        for (int ni = 0; ni < 8; ++ni)
            cn[ni] = cnorm[kbase + wnb + ni * 16 + m16];

        f32x4 acc[4][8];
#pragma unroll
        for (int mi = 0; mi < 4; ++mi)
#pragma unroll
            for (int ni = 0; ni < 8; ++ni)
                acc[mi][ni] = (f32x4){0.f, 0.f, 0.f, 0.f};

#pragma unroll 1
        for (int kt = 0; kt < KB / 64; ++kt) {       // 8 iterations
            const long ka = (long)kt * 64;
            __syncthreads();                          // LDS reuse guard
#pragma unroll
            for (int it = 0; it < 4; ++it)
                GLOAD_LDS16(aB[it] + ka, &As[it * 2048 + w * 512]);
#pragma unroll
            for (int it = 0; it < 8; ++it)
                GLOAD_LDS16(bR[it] + bOff + ka, &Bs[it * 2048 + w * 512]);
            __syncthreads();                          // drains vmcnt for glds
#pragma unroll
            for (int ks = 0; ks < 2; ++ks) {
                const int ko = koff0 ^ (ks * 32);
                half8 af[4], bf[8];
#pragma unroll
                for (int mi = 0; mi < 4; ++mi)
                    af[mi] = *(half8*)&As[rowAf + mi * 1024 + ko];
#pragma unroll
                for (int ni = 0; ni < 8; ++ni)
                    bf[ni] = *(half8*)&Bs[rowBf + ni * 1024 + ko];
#pragma unroll
                for (int mi = 0; mi < 4; ++mi)
#pragma unroll
                    for (int ni = 0; ni < 8; ++ni)
                        acc[mi][ni] = __builtin_amdgcn_mfma_f32_16x16x32_f16(
                            af[mi], bf[ni], acc[mi][ni], 0, 0, 0);
            }
        }
        // fold this tile's scores into per-lane top2 (cn already resident)
#pragma unroll
        for (int ni = 0; ni < 8; ++ni) {
            const int k = kbase + wnb + ni * 16 + m16;
#pragma unroll
            for (int mi = 0; mi < 4; ++mi)
#pragma unroll
                for (int r = 0; r < 4; ++r) {
                    const float s = fmaf(-2.0f, acc[mi][ni][r], cn[ni]);
                    const int slot = mi * 4 + r;
                    if (s < v1[slot]) {               // strict <: lowest k wins
                        v2[slot] = v1[slot];
                        i12[slot] = (k << 16) | (i12[slot] >> 16);
                        v1[slot] = s;
                    } else if (s < v2[slot]) {
                        v2[slot] = s;
                        i12[slot] = (i12[slot] & 0xffff0000) | k;
                    }
                }
        }
    }

    // cross-lane top2 reduce over the 16 lanes sharing each point row,
    // deposit per (point, column-half) into LDS
#pragma unroll
    for (int slot = 0; slot < 16; ++slot) {
        float a1 = v1[slot], a2 = v2[slot];
        int b1 = i12[slot] >> 16, b2 = i12[slot] & 0xffff;
#pragma unroll
        for (int m = 1; m < 16; m <<= 1) {
            const float c1 = __shfl_xor(a1, m, 64);
            const int   d1 = __shfl_xor(b1, m, 64);
            const float c2 = __shfl_xor(a2, m, 64);
            const int   d2 = __shfl_xor(b2, m, 64);
            if (c1 < a1 || (c1 == a1 && d1 < b1)) {
                if (a1 < c2 || (a1 == c2 && b1 < d2)) { a2 = a1; b2 = b1; }
                else { a2 = c2; b2 = d2; }
                a1 = c1; b1 = d1;
            } else {
                if (c1 < a2 || (c1 == a2 && d1 < b2)) { a2 = c1; b2 = d1; }
            }
        }
        if ((l & 15) == 0) {
            const int sm = slot >> 2, sr = slot & 3;
            const int pr = wmb + sm * 16 + (l >> 4) * 4 + sr;  // 0..127
            const int h = w & 1;                               // column half
            mv1[pr][h] = a1; mj1[pr][h] = b1;
            mv2[pr][h] = a2; mj2[pr][h] = b2;
        }
    }
    __syncthreads();
    // merge the two column-halves per point; single global write
    if (tid < 128) {
        float a1 = mv1[tid][0], a2 = mv2[tid][0];
        int b1 = mj1[tid][0], b2 = mj2[tid][0];
        const float c1 = mv1[tid][1], c2 = mv2[tid][1];
        const int   d1 = mj1[tid][1], d2 = mj2[tid][1];
        if (c1 < a1 || (c1 == a1 && d1 < b1)) {
            if (a1 < c2 || (a1 == c2 && b1 < d2)) { a2 = a1; b2 = b1; }
            else { a2 = c2; b2 = d2; }
            a1 = c1; b1 = d1;
        } else {
            if (c1 < a2 || (c1 == a2 && d1 < b2)) { a2 = c1; b2 = d1; }
        }
        const size_t o = (size_t)nsplit * N_PTS + pbase + tid;
        pv1[o] = a1; pi1[o] = b1; pv2[o] = a2; pi2[o] = b2;
    }
}

// ---------------------------------------------------------------- gather
// R17 version (verified): wave-per-point; partials merge + rare fp64
// rescore; out_q = cb[bi]; psums[p] = |z|^2 + s_final.
__global__ __launch_bounds__(256) void gather_kernel(
    const float* __restrict__ z_e, const float* __restrict__ cb,
    const float* __restrict__ pv1, const int* __restrict__ pi1,
    const float* __restrict__ pv2, const int* __restrict__ pi2,
    float* __restrict__ out_q, float* __restrict__ out_idx,
    unsigned int* __restrict__ counts, float* __restrict__ psums) {
    const int wid  = threadIdx.x >> 6;          // wave 0..3
    const int lane = threadIdx.x & 63;
    const int p    = blockIdx.x * 4 + wid;      // point index

    const float zn = psums[p];                  // |z_p|^2 (written by prep)

    // lane s (s < 16) holds split s's partials
    float lv1 = 3.0e38f, lv2 = 3.0e38f;
    int   li1 = 0x7fffffff, li2 = 0x7fffffff;
    if (lane < NSPLIT) {
        const size_t o = (size_t)lane * N_PTS + p;
        lv1 = pv1[o]; li1 = pi1[o];
        lv2 = pv2[o]; li2 = pi2[o];
    }

    // merge scan (every lane computes the same values via broadcasts)
    float bv = 3.0e38f; int bi = 0x7fffffff;
#pragma unroll
    for (int s = 0; s < NSPLIT; ++s) {
        const float v = __shfl(lv1, s, 64);
        const int   i = __shfl(li1, s, 64);
        if (v < bv || (v == bv && i < bi)) { bv = v; bi = i; }
    }
    float second = 3.0e38f;
    int cand[8]; int nc = 1; cand[0] = bi;
#pragma unroll
    for (int s = 0; s < NSPLIT; ++s) {
        const float v  = __shfl(lv1, s, 64);
        const int   i  = __shfl(li1, s, 64);
        const float w2 = __shfl(lv2, s, 64);
        const int   j  = __shfl(li2, s, 64);
        if (i != bi) {
            if (v < second) second = v;
            if (v <= bv + MARGIN && nc < 8) cand[nc++] = i;
        }
        if (j != bi) {
            if (w2 < second) second = w2;
            if (w2 <= bv + MARGIN && nc < 8) cand[nc++] = j;
        }
    }

    float sfinal = bv;                          // screened |c|^2 - 2<z,c>
    if (second - bv <= MARGIN && nc > 1) {      // wave-uniform condition
        double bestv = 1.0e300; int besti = 0x7fffffff;
        for (int c = 0; c < nc; ++c) {
            const int k = cand[c];
            double part = 0.0;
#pragma unroll
            for (int j = 0; j < 8; ++j) {
                const int d = lane * 8 + j;
                const double cv = (double)cb[(size_t)k * DIM + d];
                const double zv = (double)z_e[(size_t)p * DIM + d];
                part += cv * cv - 2.0 * zv * cv;
            }
#pragma unroll
            for (int o = 32; o > 0; o >>= 1) part += __shfl_down(part, o, 64);
            const double s = __shfl(part, 0, 64);
            if (s < bestv || (s == bestv && k < besti)) { bestv = s; besti = k; }
        }
        bi = besti;
        sfinal = (float)bestv;
    }

    // straight-through output: z + (c - z) == c to 1 ulp (bf16-compare-safe)
    const float4* cp = (const float4*)(cb + (size_t)bi * DIM);
    float4* op = (float4*)(out_q + (size_t)p * DIM);
    op[lane * 2]     = cp[lane * 2];
    op[lane * 2 + 1] = cp[lane * 2 + 1];
    if (lane == 0) {
        psums[p] = zn + sfinal;                 // |z - c|^2
        out_idx[p] = (float)bi;
        atomicAdd(&counts[bi], 1u);
    }
}

// ---------------------------------------------------------------- finalize
__global__ __launch_bounds__(256) void finalize_kernel(
    const unsigned int* __restrict__ counts, const float* __restrict__ psums,
    float* __restrict__ out_scalars) {
    const int t = threadIdx.x;
    float ent = 0.0f;
    for (int b = t; b < K_CODES; b += 256) {
        const float pr = (float)counts[b] * (1.0f / 16384.0f);
        ent += pr * logf(pr + 1e-10f);
    }
    float ss = 0.0f;
    for (int i = t; i < N_PTS; i += 256) ss += psums[i];
#pragma unroll
    for (int off = 32; off > 0; off >>= 1) {
        ent += __shfl_down(ent, off, 64);
        ss += __shfl_down(ss, off, 64);
    }
    __shared__ float re[4], rs[4];
    if ((t & 63) == 0) { re[t >> 6] = ent; rs[t >> 6] = ss; }
    __syncthreads();
    if (t == 0) {
        const float loss = (rs[0] + rs[1] + rs[2] + rs[3]) * (1.0f / NELEM_F);
        out_scalars[0] = loss;
        out_scalars[1] = loss;
        out_scalars[2] = expf(-(re[0] + re[1] + re[2] + re[3]));
    }
}

// ================================================================ fallback
// round-1 pure fp32 path (used only if ws_size < WS_NEED)
#define FB_SPLIT 4
#define FB_KS    (K_CODES / FB_SPLIT)
#define FB_MT    128
#define FB_KT    128
#define FB_DT    32
#define FB_PITCH 36

__global__ __launch_bounds__(256, 2) void fb_dist_argmin_kernel(
    const float* __restrict__ z_e, const float* __restrict__ cb,
    const float* __restrict__ cnorm,
    float* __restrict__ pmin, int* __restrict__ pidx) {
    __shared__ float xs[FB_MT * FB_PITCH];
    __shared__ float cs[FB_KT * FB_PITCH];
    const int tid = threadIdx.x;
    const int tx = tid & 15, ty = tid >> 4;
    const int pbase = blockIdx.x * FB_MT;
    const int kbase0 = blockIdx.y * FB_KS;
    const int scol = (tid & 7) * 4, srow0 = tid >> 3;
    float mn[8], acc[8][8];
    int mi[8];
#pragma unroll
    for (int i = 0; i < 8; ++i) { mn[i] = 3.0e38f; mi[i] = 0; }
    for (int kt = 0; kt < FB_KS / FB_KT; ++kt) {
        const int kbase = kbase0 + kt * FB_KT;
#pragma unroll
        for (int i = 0; i < 8; ++i)
#pragma unroll
            for (int j = 0; j < 8; ++j) acc[i][j] = 0.0f;
        for (int dc = 0; dc < DIM / FB_DT; ++dc) {
            const int dbase = dc * FB_DT;
            __syncthreads();
#pragma unroll
            for (int it = 0; it < 4; ++it) {
                const int row = srow0 + it * 32;
                *(float4*)(xs + row * FB_PITCH + scol) =
                    *(const float4*)(z_e + (size_t)(pbase + row) * DIM + dbase + scol);
                *(float4*)(cs + row * FB_PITCH + scol) =
                    *(const float4*)(cb + (size_t)(kbase + row) * DIM + dbase + scol);
            }
            __syncthreads();
#pragma unroll 2
            for (int dd = 0; dd < FB_DT; dd += 4) {
                float4 xv[8], cv[8];
#pragma unroll
                for (int i = 0; i < 8; ++i)
                    xv[i] = *(const float4*)(xs + (ty + 16 * i) * FB_PITCH + dd);
#pragma unroll
                for (int j = 0; j < 8; ++j)
                    cv[j] = *(const float4*)(cs + (tx + 16 * j) * FB_PITCH + dd);
#pragma unroll
                for (int i = 0; i < 8; ++i)
#pragma unroll
                    for (int j = 0; j < 8; ++j)
                        acc[i][j] += xv[i].x * cv[j].x + xv[i].y * cv[j].y +
                                     xv[i].z * cv[j].z + xv[i].w * cv[j].w;
            }
        }
#pragma unroll
        for (int j = 0; j < 8; ++j) {
            const int k = kbase + tx + 16 * j;
            const float cn = cnorm[k];
#pragma unroll
            for (int i = 0; i < 8; ++i) {
                const float s = cn - 2.0f * acc[i][j];
                if (s < mn[i]) { mn[i] = s; mi[i] = k; }
            }
        }
    }
    float* rmin = xs;
    int* ridx = (int*)cs;
    __syncthreads();
#pragma unroll
    for (int i = 0; i < 8; ++i) {
        const int p = ty + 16 * i;
        rmin[p * 16 + tx] = mn[i];
        ridx[p * 16 + tx] = mi[i];
    }
    __syncthreads();
    if (tid < FB_MT) {
        float best = rmin[tid * 16];
        int bi = ridx[tid * 16];
#pragma unroll
        for (int t = 1; t < 16; ++t) {
            const float v = rmin[tid * 16 + t];
            const int k2 = ridx[tid * 16 + t];
            if (v < best || (v == best && k2 < bi)) { best = v; bi = k2; }
        }
        pmin[(size_t)blockIdx.y * N_PTS + pbase + tid] = best;
        pidx[(size_t)blockIdx.y * N_PTS + pbase + tid] = bi;
    }
}

__global__ __launch_bounds__(128) void fb_gather_kernel(
    const float* __restrict__ z_e, const float* __restrict__ cb,
    const float* __restrict__ pmin, const int* __restrict__ pidx,
    float* __restrict__ out_q, float* __restrict__ out_idx,
    unsigned int* __restrict__ counts, float* __restrict__ psums) {
    const int p = blockIdx.x;
    const int t = threadIdx.x;
    float best = pmin[p];
    int bi = pidx[p];
#pragma unroll
    for (int s = 1; s < FB_SPLIT; ++s) {
        const float v = pmin[(size_t)s * N_PTS + p];
        const int k2 = pidx[(size_t)s * N_PTS + p];
        if (v < best || (v == best && k2 < bi)) { best = v; bi = k2; }
    }
    const float4 z = *(const float4*)(z_e + (size_t)p * DIM + t * 4);
    const float4 c = *(const float4*)(cb + (size_t)bi * DIM + t * 4);
    float4 d, o;
    d.x = c.x - z.x; d.y = c.y - z.y; d.z = c.z - z.z; d.w = c.w - z.w;
    o.x = z.x + d.x; o.y = z.y + d.y; o.z = z.z + d.z; o.w = z.w + d.w;
    *(float4*)(out_q + (size_t)p * DIM + t * 4) = o;
    float ls = d.x * d.x + d.y * d.y + d.z * d.z + d.w * d.w;
#pragma unroll
    for (int off = 32; off > 0; off >>= 1) ls += __shfl_down(ls, off, 64);
    __shared__ float red[2];
    if ((t & 63) == 0) red[t >> 6] = ls;
    __syncthreads();
    if (t == 0) {
        psums[p] = red[0] + red[1];
        out_idx[p] = (float)bi;
        atomicAdd(&counts[bi], 1u);
    }
}

// ================================================================ launch
extern "C" void kernel_launch(void* const* d_in, const int* in_sizes, int n_in,
                              void* d_out, int out_size, void* d_ws, size_t ws_size,
                              hipStream_t stream) {
    const float* z_e = (const float*)d_in[0];
    const float* cb  = (const float*)d_in[1];
    float* out = (float*)d_out;
    char* ws = (char*)d_ws;

    if (ws_size >= WS_NEED) {
        _Float16* A3      = (_Float16*)(ws + OFF_A3);
        _Float16* B3      = (_Float16*)(ws + OFF_B3);
        float* cnorm      = (float*)(ws + OFF_CN);
        float* pv1        = (float*)(ws + OFF_PV1);
        int* pi1          = (int*)(ws + OFF_PI1);
        float* pv2        = (float*)(ws + OFF_PV2);
        int* pi2          = (int*)(ws + OFF_PI2);
        float* psums      = (float*)(ws + OFF_PSUM);
        unsigned int* cnt = (unsigned int*)(ws + OFF_CNT);

        prep_all<<<1024, 256, 0, stream>>>(z_e, cb, A3, B3, cnorm, cnt, psums);
        dim3 g(N_PTS / 128, NSPLIT);                   // 128 x 16 blocks
        score_kernel<<<g, 256, 0, stream>>>(A3, B3, cnorm, pv1, pi1, pv2, pi2);
        gather_kernel<<<N_PTS / 4, 256, 0, stream>>>(z_e, cb, pv1, pi1, pv2, pi2,
                                                     out, out + OUT0_N, cnt, psums);
        finalize_kernel<<<1, 256, 0, stream>>>(cnt, psums, out + OUT0_N + N_PTS);
    } else {
        // round-1 fp32 fallback (<700 KB ws)
        float* cnorm      = (float*)ws;
        float* pmin       = (float*)(ws + 32768);
        int* pidx         = (int*)(ws + 32768 + 262144);
        unsigned int* cnt = (unsigned int*)(ws + 32768 + 2 * 262144);
        float* psums      = (float*)(ws + 32768 + 2 * 262144 + 32768);

        hipMemsetAsync(cnt, 0, 32768, stream);
        cnorm_kernel<<<K_CODES, 128, 0, stream>>>(cb, cnorm);
        dim3 grid1(N_PTS / FB_MT, FB_SPLIT);
        fb_dist_argmin_kernel<<<grid1, 256, 0, stream>>>(z_e, cb, cnorm, pmin, pidx);
        fb_gather_kernel<<<N_PTS, 128, 0, stream>>>(z_e, cb, pmin, pidx,
                                                    out, out + OUT0_N, cnt, psums);
        finalize_kernel<<<1, 256, 0, stream>>>(cnt, psums, out + OUT0_N + N_PTS);
    }
}

// Round 12
// 345.984 us; speedup vs baseline: 1.0604x; 1.0604x over previous
//
#include <hip/hip_runtime.h>

// ---------------------------------------------------------------------------
// VectorQuantizer: N=16384 points x K=8192 codes x D=512 fp32.
// R19 == R17 restored (best verified: 330.9us, absmax 4.9e-4).
// R18's 128x256 wide tile regressed (210->229us score): LDS 52KB + (256,2)
// dropped residency 3->2 blocks/CU and the lost wave-level overlap (m114
// mechanism) outweighed barrier amortization. (256,3) wide-tile can't fit
// the register budget (256 regs > ~170 at 3 waves/SIMD). Design space at
// this structure is closed:
//   - 512-thr 8-phase (R8-R11): spill-clamp, 8.7% MfmaUtil
//   - stage-ahead (R14): correctness failure
//   - wide tile (R18): occupancy cliff
//   - cn-hoist (R16): +6us  [kept]
//   - wave-per-point gather (R15): +19us  [kept]
// Final config: score = R7 structure + cn-hoist (210us, 28.3% MfmaUtil,
// 3 blk/CU); gather = wave-per-point + de-redundancy; prep = fused
// grid-stride with |z|^2 -> psums.
// Fallback (small ws): round-1 pure-fp32 VALU kernel (known-correct).
// ---------------------------------------------------------------------------

#define N_PTS   16384
#define DIM     512
#define K_CODES 8192
#define KB      512                   // screening K (hi only)
#define NSPLIT  16                    // code splits (512 codes each)
#define OUT0_N  (N_PTS * DIM)
#define NELEM_F (8388608.0f)
#define MARGIN  1.5e-2f

typedef _Float16 half8 __attribute__((ext_vector_type(8)));
typedef _Float16 f16x4 __attribute__((ext_vector_type(4)));
typedef float    f32x4 __attribute__((ext_vector_type(4)));

// fast-path workspace layout (bytes)
#define SZ_A3    (16384UL * 512 * 2)               // 16.8 MB
#define SZ_B3    (8192UL * 512 * 2)                // 8.4 MB
#define OFF_A3   0UL
#define OFF_B3   (OFF_A3 + SZ_A3)
#define OFF_CN   (OFF_B3 + SZ_B3)                  // cnorm 32 KB
#define OFF_PV1  (OFF_CN + 32768UL)
#define SZ_P     (16UL * 16384 * 4)                // 1 MB each
#define OFF_PI1  (OFF_PV1 + SZ_P)
#define OFF_PV2  (OFF_PI1 + SZ_P)
#define OFF_PI2  (OFF_PV2 + SZ_P)
#define OFF_PSUM (OFF_PI2 + SZ_P)                  // psums 64 KB (|z|^2 -> loss)
#define OFF_CNT  (OFF_PSUM + 65536UL)              // counts 32 KB
#define WS_NEED  (OFF_CNT + 32768UL)

#define GLOAD_LDS16(g, l) \
    __builtin_amdgcn_global_load_lds( \
        (const __attribute__((address_space(1))) unsigned int*)(g), \
        (__attribute__((address_space(3))) unsigned int*)(l), 16, 0, 0)

// ---------------------------------------------------------------- prep (fused)
// Wave-per-row for z_e (cast + |z|^2 -> psums) and cb (cast + cnorm);
// counts zeroed grid-stride. 1024 blocks x 256 threads.
__global__ __launch_bounds__(256) void prep_all(const float* __restrict__ z_e,
                                                const float* __restrict__ cb,
                                                _Float16* __restrict__ A3,
                                                _Float16* __restrict__ B3,
                                                float* __restrict__ cnorm,
                                                unsigned int* __restrict__ counts,
                                                float* __restrict__ psums) {
    const int tid   = threadIdx.x;
    const int gid0  = blockIdx.x * 256 + tid;
    const int gsize = gridDim.x * 256;

    for (int i = gid0; i < K_CODES; i += gsize) counts[i] = 0u;

    const int lane   = tid & 63;
    const int wave   = gid0 >> 6;                  // global wave id
    const int nwaves = gsize >> 6;

    for (int r = wave; r < N_PTS; r += nwaves) {
        const float* src = z_e + (size_t)r * DIM + lane * 8;
        const float4 v0 = *(const float4*)(src);
        const float4 v1 = *(const float4*)(src + 4);
        f16x4 h0, h1;
        h0[0] = (_Float16)v0.x; h0[1] = (_Float16)v0.y;
        h0[2] = (_Float16)v0.z; h0[3] = (_Float16)v0.w;
        h1[0] = (_Float16)v1.x; h1[1] = (_Float16)v1.y;
        h1[2] = (_Float16)v1.z; h1[3] = (_Float16)v1.w;
        _Float16* dst = A3 + (size_t)r * 512 + lane * 8;
        *(f16x4*)(dst)     = h0;
        *(f16x4*)(dst + 4) = h1;
        float s = v0.x * v0.x + v0.y * v0.y + v0.z * v0.z + v0.w * v0.w
                + v1.x * v1.x + v1.y * v1.y + v1.z * v1.z + v1.w * v1.w;
#pragma unroll
        for (int o = 32; o > 0; o >>= 1) s += __shfl_down(s, o, 64);
        if (lane == 0) psums[r] = s;               // |z_r|^2 (consumed by gather)
    }

    for (int r = wave; r < K_CODES; r += nwaves) {
        const float* src = cb + (size_t)r * DIM + lane * 8;
        const float4 v0 = *(const float4*)(src);
        const float4 v1 = *(const float4*)(src + 4);
        f16x4 h0, h1;
        h0[0] = (_Float16)v0.x; h0[1] = (_Float16)v0.y;
        h0[2] = (_Float16)v0.z; h0[3] = (_Float16)v0.w;
        h1[0] = (_Float16)v1.x; h1[1] = (_Float16)v1.y;
        h1[2] = (_Float16)v1.z; h1[3] = (_Float16)v1.w;
        _Float16* dst = B3 + (size_t)r * 512 + lane * 8;
        *(f16x4*)(dst)     = h0;
        *(f16x4*)(dst + 4) = h1;
        float s = v0.x * v0.x + v0.y * v0.y + v0.z * v0.z + v0.w * v0.w
                + v1.x * v1.x + v1.y * v1.y + v1.z * v1.z + v1.w * v1.w;
#pragma unroll
        for (int o = 32; o > 0; o >>= 1) s += __shfl_down(s, o, 64);
        if (lane == 0) cnorm[r] = s;
    }
}

// ---------------------------------------------------------------- cnorm (fallback)
__global__ __launch_bounds__(128) void cnorm_kernel(const float* __restrict__ cb,
                                                    float* __restrict__ cnorm) {
    const int k = blockIdx.x;
    const int t = threadIdx.x;
    const float4 v = *(const float4*)(cb + (size_t)k * DIM + t * 4);
    float s = v.x * v.x + v.y * v.y + v.z * v.z + v.w * v.w;
#pragma unroll
    for (int o = 32; o > 0; o >>= 1) s += __shfl_down(s, o, 64);
    __shared__ float red[2];
    if ((t & 63) == 0) red[t >> 6] = s;
    __syncthreads();
    if (t == 0) cnorm[k] = red[0] + red[1];
}

// ---------------------------------------------------------------- score GEMM
// [VERIFIED] 128x128 tile, BK=64, global_load_lds w=16, 4 waves 2x2, each
// wave 64x64 via 4x4 of 16x16x32 f16 MFMA, __launch_bounds__(256,3) ->
// 3 blocks/CU (the occupancy that carries the implicit wave overlap).
// LDS XOR-swizzled at 16B-chunk granularity (conflicts -> 0). Per-nt cnorm
// loads hoisted before the kt-loop (R16). Top-2 per point-slot; inter-wave
// LDS merge epilogue.
__global__ __launch_bounds__(256, 3) void score_kernel(
    const _Float16* __restrict__ A3, const _Float16* __restrict__ B3,
    const float* __restrict__ cnorm,
    float* __restrict__ pv1, int* __restrict__ pi1,
    float* __restrict__ pv2, int* __restrict__ pi2) {
    __shared__ _Float16 As[128 * 64];   // 16 KB
    __shared__ _Float16 Bs[128 * 64];   // 16 KB
    __shared__ float mv1[128][2], mv2[128][2];
    __shared__ int   mj1[128][2], mj2[128][2];

    const int tid = threadIdx.x;
    const int w = tid >> 6;             // wave 0..3
    const int l = tid & 63;
    const int pbase = blockIdx.x * 128;
    const int nsplit = blockIdx.y;      // 0..15
    const int wmb = (w >> 1) * 64;      // wave m offset
    const int wnb = (w & 1) * 64;       // wave n offset
    const int srow = w * 8 + (l >> 3);  // staging row (+ it*32)
    const int scolh = (((l & 7) ^ ((l >> 3) & 7)) * 8);   // swizzled src col

    const _Float16* aB[4];
    const _Float16* bR[4];
#pragma unroll
    for (int it = 0; it < 4; ++it) {
        aB[it] = A3 + (long)(pbase + it * 32 + srow) * 512 + scolh;
        bR[it] = B3 + (long)(it * 32 + srow) * 512 + scolh;
    }

    const int q = l >> 4, x7 = l & 7, m16 = l & 15;
    const int koff0 = ((q ^ x7) * 8);          // ks=0 chunk offset (halves)
    const int rowAf = (wmb + m16) * 64;        // + mi*1024
    const int rowBf = (wnb + m16) * 64;        // + ni*1024

    float v1[16], v2[16];
    int i12[16];                               // (i1<<16) | i2, codes < 8192
#pragma unroll
    for (int s = 0; s < 16; ++s) { v1[s] = 3.0e38f; v2[s] = 3.0e38f; i12[s] = 0; }

#pragma unroll 1
    for (int nt = 0; nt < 4; ++nt) {
        const int kbase = nsplit * 512 + nt * 128;   // code row base
        const long bOff = (long)kbase * 512;
        // hoisted cnorm loads: issue now, consumed at the fold (8 kt of cover)
        float cn[4];
#pragma unroll
        for (int ni = 0; ni < 4; ++ni)
            cn[ni] = cnorm[kbase + wnb + ni * 16 + m16];

        f32x4 acc[4][4];
#pragma unroll
        for (int mi = 0; mi < 4; ++mi)
#pragma unroll
            for (int ni = 0; ni < 4; ++ni)
                acc[mi][ni] = (f32x4){0.f, 0.f, 0.f, 0.f};

#pragma unroll 1
        for (int kt = 0; kt < KB / 64; ++kt) {       // 8 iterations
            const long ka = (long)kt * 64;
            __syncthreads();                          // LDS reuse guard
#pragma unroll
            for (int it = 0; it < 4; ++it)
                GLOAD_LDS16(aB[it] + ka, &As[it * 2048 + w * 512]);
#pragma unroll
            for (int it = 0; it < 4; ++it)
                GLOAD_LDS16(bR[it] + bOff + ka, &Bs[it * 2048 + w * 512]);
            __syncthreads();                          // drains vmcnt for glds
#pragma unroll
            for (int ks = 0; ks < 2; ++ks) {
                const int ko = koff0 ^ (ks * 32);
                half8 af[4], bf[4];
#pragma unroll
                for (int mi = 0; mi < 4; ++mi)
                    af[mi] = *(half8*)&As[rowAf + mi * 1024 + ko];
#pragma unroll
                for (int ni = 0; ni < 4; ++ni)
                    bf[ni] = *(half8*)&Bs[rowBf + ni * 1024 + ko];
#pragma unroll
                for (int mi = 0; mi < 4; ++mi)
#pragma unroll
                    for (int ni = 0; ni < 4; ++ni)
                        acc[mi][ni] = __builtin_amdgcn_mfma_f32_16x16x32_f16(
                            af[mi], bf[ni], acc[mi][ni], 0, 0, 0);
            }
        }
        // fold this tile's scores into per-lane top2 (cn already resident)
#pragma unroll
        for (int ni = 0; ni < 4; ++ni) {
            const int k = kbase + wnb + ni * 16 + m16;
#pragma unroll
            for (int mi = 0; mi < 4; ++mi)
#pragma unroll
                for (int r = 0; r < 4; ++r) {
                    const float s = fmaf(-2.0f, acc[mi][ni][r], cn[ni]);
                    const int slot = mi * 4 + r;
                    if (s < v1[slot]) {               // strict <: lowest k wins
                        v2[slot] = v1[slot];
                        i12[slot] = (k << 16) | (i12[slot] >> 16);
                        v1[slot] = s;
                    } else if (s < v2[slot]) {
                        v2[slot] = s;
                        i12[slot] = (i12[slot] & 0xffff0000) | k;
                    }
                }
        }
    }

    // cross-lane top2 reduce over the 16 lanes sharing each point row,
    // deposit per (point, column-half) into LDS
#pragma unroll
    for (int slot = 0; slot < 16; ++slot) {
        float a1 = v1[slot], a2 = v2[slot];
        int b1 = i12[slot] >> 16, b2 = i12[slot] & 0xffff;
#pragma unroll
        for (int m = 1; m < 16; m <<= 1) {
            const float c1 = __shfl_xor(a1, m, 64);
            const int   d1 = __shfl_xor(b1, m, 64);
            const float c2 = __shfl_xor(a2, m, 64);
            const int   d2 = __shfl_xor(b2, m, 64);
            if (c1 < a1 || (c1 == a1 && d1 < b1)) {
                if (a1 < c2 || (a1 == c2 && b1 < d2)) { a2 = a1; b2 = b1; }
                else { a2 = c2; b2 = d2; }
                a1 = c1; b1 = d1;
            } else {
                if (c1 < a2 || (c1 == a2 && d1 < b2)) { a2 = c1; b2 = d1; }
            }
        }
        if ((l & 15) == 0) {
            const int sm = slot >> 2, sr = slot & 3;
            const int pr = wmb + sm * 16 + (l >> 4) * 4 + sr;  // 0..127
            const int h = w & 1;                               // column half
            mv1[pr][h] = a1; mj1[pr][h] = b1;
            mv2[pr][h] = a2; mj2[pr][h] = b2;
        }
    }
    __syncthreads();
    // merge the two column-halves per point; single global write
    if (tid < 128) {
        float a1 = mv1[tid][0], a2 = mv2[tid][0];
        int b1 = mj1[tid][0], b2 = mj2[tid][0];
        const float c1 = mv1[tid][1], c2 = mv2[tid][1];
        const int   d1 = mj1[tid][1], d2 = mj2[tid][1];
        if (c1 < a1 || (c1 == a1 && d1 < b1)) {
            if (a1 < c2 || (a1 == c2 && b1 < d2)) { a2 = a1; b2 = b1; }
            else { a2 = c2; b2 = d2; }
            a1 = c1; b1 = d1;
        } else {
            if (c1 < a2 || (c1 == a2 && d1 < b2)) { a2 = c1; b2 = d1; }
        }
        const size_t o = (size_t)nsplit * N_PTS + pbase + tid;
        pv1[o] = a1; pi1[o] = b1; pv2[o] = a2; pi2[o] = b2;
    }
}

// ---------------------------------------------------------------- gather
// Wave-per-point (4 points per 256-thread block): partials merge via
// __shfl broadcasts (same s=0..15 scan order), rare wave-uniform fp64
// rescore, out_q = cb[bi], psums[p] = |z|^2 + s_final.
__global__ __launch_bounds__(256) void gather_kernel(
    const float* __restrict__ z_e, const float* __restrict__ cb,
    const float* __restrict__ pv1, const int* __restrict__ pi1,
    const float* __restrict__ pv2, const int* __restrict__ pi2,
    float* __restrict__ out_q, float* __restrict__ out_idx,
    unsigned int* __restrict__ counts, float* __restrict__ psums) {
    const int wid  = threadIdx.x >> 6;          // wave 0..3
    const int lane = threadIdx.x & 63;
    const int p    = blockIdx.x * 4 + wid;      // point index

    const float zn = psums[p];                  // |z_p|^2 (written by prep)

    // lane s (s < 16) holds split s's partials
    float lv1 = 3.0e38f, lv2 = 3.0e38f;
    int   li1 = 0x7fffffff, li2 = 0x7fffffff;
    if (lane < NSPLIT) {
        const size_t o = (size_t)lane * N_PTS + p;
        lv1 = pv1[o]; li1 = pi1[o];
        lv2 = pv2[o]; li2 = pi2[o];
    }

    // merge scan (every lane computes the same values via broadcasts)
    float bv = 3.0e38f; int bi = 0x7fffffff;
#pragma unroll
    for (int s = 0; s < NSPLIT; ++s) {
        const float v = __shfl(lv1, s, 64);
        const int   i = __shfl(li1, s, 64);
        if (v < bv || (v == bv && i < bi)) { bv = v; bi = i; }
    }
    float second = 3.0e38f;
    int cand[8]; int nc = 1; cand[0] = bi;
#pragma unroll
    for (int s = 0; s < NSPLIT; ++s) {
        const float v  = __shfl(lv1, s, 64);
        const int   i  = __shfl(li1, s, 64);
        const float w2 = __shfl(lv2, s, 64);
        const int   j  = __shfl(li2, s, 64);
        if (i != bi) {
            if (v < second) second = v;
            if (v <= bv + MARGIN && nc < 8) cand[nc++] = i;
        }
        if (j != bi) {
            if (w2 < second) second = w2;
            if (w2 <= bv + MARGIN && nc < 8) cand[nc++] = j;
        }
    }

    float sfinal = bv;                          // screened |c|^2 - 2<z,c>
    if (second - bv <= MARGIN && nc > 1) {      // wave-uniform condition
        double bestv = 1.0e300; int besti = 0x7fffffff;
        for (int c = 0; c < nc; ++c) {
            const int k = cand[c];
            double part = 0.0;
#pragma unroll
            for (int j = 0; j < 8; ++j) {
                const int d = lane * 8 + j;
                const double cv = (double)cb[(size_t)k * DIM + d];
                const double zv = (double)z_e[(size_t)p * DIM + d];
                part += cv * cv - 2.0 * zv * cv;
            }
#pragma unroll
            for (int o = 32; o > 0; o >>= 1) part += __shfl_down(part, o, 64);
            const double s = __shfl(part, 0, 64);
            if (s < bestv || (s == bestv && k < besti)) { bestv = s; besti = k; }
        }
        bi = besti;
        sfinal = (float)bestv;
    }

    // straight-through output: z + (c - z) == c to 1 ulp (bf16-compare-safe)
    const float4* cp = (const float4*)(cb + (size_t)bi * DIM);
    float4* op = (float4*)(out_q + (size_t)p * DIM);
    op[lane * 2]     = cp[lane * 2];
    op[lane * 2 + 1] = cp[lane * 2 + 1];
    if (lane == 0) {
        psums[p] = zn + sfinal;                 // |z - c|^2
        out_idx[p] = (float)bi;
        atomicAdd(&counts[bi], 1u);
    }
}

// ---------------------------------------------------------------- finalize
__global__ __launch_bounds__(256) void finalize_kernel(
    const unsigned int* __restrict__ counts, const float* __restrict__ psums,
    float* __restrict__ out_scalars) {
    const int t = threadIdx.x;
    float ent = 0.0f;
    for (int b = t; b < K_CODES; b += 256) {
        const float pr = (float)counts[b] * (1.0f / 16384.0f);
        ent += pr * logf(pr + 1e-10f);
    }
    float ss = 0.0f;
    for (int i = t; i < N_PTS; i += 256) ss += psums[i];
#pragma unroll
    for (int off = 32; off > 0; off >>= 1) {
        ent += __shfl_down(ent, off, 64);
        ss += __shfl_down(ss, off, 64);
    }
    __shared__ float re[4], rs[4];
    if ((t & 63) == 0) { re[t >> 6] = ent; rs[t >> 6] = ss; }
    __syncthreads();
    if (t == 0) {
        const float loss = (rs[0] + rs[1] + rs[2] + rs[3]) * (1.0f / NELEM_F);
        out_scalars[0] = loss;
        out_scalars[1] = loss;
        out_scalars[2] = expf(-(re[0] + re[1] + re[2] + re[3]));
    }
}

// ================================================================ fallback
// round-1 pure fp32 path (used only if ws_size < WS_NEED)
#define FB_SPLIT 4
#define FB_KS    (K_CODES / FB_SPLIT)
#define FB_MT    128
#define FB_KT    128
#define FB_DT    32
#define FB_PITCH 36

__global__ __launch_bounds__(256, 2) void fb_dist_argmin_kernel(
    const float* __restrict__ z_e, const float* __restrict__ cb,
    const float* __restrict__ cnorm,
    float* __restrict__ pmin, int* __restrict__ pidx) {
    __shared__ float xs[FB_MT * FB_PITCH];
    __shared__ float cs[FB_KT * FB_PITCH];
    const int tid = threadIdx.x;
    const int tx = tid & 15, ty = tid >> 4;
    const int pbase = blockIdx.x * FB_MT;
    const int kbase0 = blockIdx.y * FB_KS;
    const int scol = (tid & 7) * 4, srow0 = tid >> 3;
    float mn[8], acc[8][8];
    int mi[8];
#pragma unroll
    for (int i = 0; i < 8; ++i) { mn[i] = 3.0e38f; mi[i] = 0; }
    for (int kt = 0; kt < FB_KS / FB_KT; ++kt) {
        const int kbase = kbase0 + kt * FB_KT;
#pragma unroll
        for (int i = 0; i < 8; ++i)
#pragma unroll
            for (int j = 0; j < 8; ++j) acc[i][j] = 0.0f;
        for (int dc = 0; dc < DIM / FB_DT; ++dc) {
            const int dbase = dc * FB_DT;
            __syncthreads();
#pragma unroll
            for (int it = 0; it < 4; ++it) {
                const int row = srow0 + it * 32;
                *(float4*)(xs + row * FB_PITCH + scol) =
                    *(const float4*)(z_e + (size_t)(pbase + row) * DIM + dbase + scol);
                *(float4*)(cs + row * FB_PITCH + scol) =
                    *(const float4*)(cb + (size_t)(kbase + row) * DIM + dbase + scol);
            }
            __syncthreads();
#pragma unroll 2
            for (int dd = 0; dd < FB_DT; dd += 4) {
                float4 xv[8], cv[8];
#pragma unroll
                for (int i = 0; i < 8; ++i)
                    xv[i] = *(const float4*)(xs + (ty + 16 * i) * FB_PITCH + dd);
#pragma unroll
                for (int j = 0; j < 8; ++j)
                    cv[j] = *(const float4*)(cs + (tx + 16 * j) * FB_PITCH + dd);
#pragma unroll
                for (int i = 0; i < 8; ++i)
#pragma unroll
                    for (int j = 0; j < 8; ++j)
                        acc[i][j] += xv[i].x * cv[j].x + xv[i].y * cv[j].y +
                                     xv[i].z * cv[j].z + xv[i].w * cv[j].w;
            }
        }
#pragma unroll
        for (int j = 0; j < 8; ++j) {
            const int k = kbase + tx + 16 * j;
            const float cn = cnorm[k];
#pragma unroll
            for (int i = 0; i < 8; ++i) {
                const float s = cn - 2.0f * acc[i][j];
                if (s < mn[i]) { mn[i] = s; mi[i] = k; }
            }
        }
    }
    float* rmin = xs;
    int* ridx = (int*)cs;
    __syncthreads();
#pragma unroll
    for (int i = 0; i < 8; ++i) {
        const int p = ty + 16 * i;
        rmin[p * 16 + tx] = mn[i];
        ridx[p * 16 + tx] = mi[i];
    }
    __syncthreads();
    if (tid < FB_MT) {
        float best = rmin[tid * 16];
        int bi = ridx[tid * 16];
#pragma unroll
        for (int t = 1; t < 16; ++t) {
            const float v = rmin[tid * 16 + t];
            const int k2 = ridx[tid * 16 + t];
            if (v < best || (v == best && k2 < bi)) { best = v; bi = k2; }
        }
        pmin[(size_t)blockIdx.y * N_PTS + pbase + tid] = best;
        pidx[(size_t)blockIdx.y * N_PTS + pbase + tid] = bi;
    }
}

__global__ __launch_bounds__(128) void fb_gather_kernel(
    const float* __restrict__ z_e, const float* __restrict__ cb,
    const float* __restrict__ pmin, const int* __restrict__ pidx,
    float* __restrict__ out_q, float* __restrict__ out_idx,
    unsigned int* __restrict__ counts, float* __restrict__ psums) {
    const int p = blockIdx.x;
    const int t = threadIdx.x;
    float best = pmin[p];
    int bi = pidx[p];
#pragma unroll
    for (int s = 1; s < FB_SPLIT; ++s) {
        const float v = pmin[(size_t)s * N_PTS + p];
        const int k2 = pidx[(size_t)s * N_PTS + p];
        if (v < best || (v == best && k2 < bi)) { best = v; bi = k2; }
    }
    const float4 z = *(const float4*)(z_e + (size_t)p * DIM + t * 4);
    const float4 c = *(const float4*)(cb + (size_t)bi * DIM + t * 4);
    float4 d, o;
    d.x = c.x - z.x; d.y = c.y - z.y; d.z = c.z - z.z; d.w = c.w - z.w;
    o.x = z.x + d.x; o.y = z.y + d.y; o.z = z.z + d.z; o.w = z.w + d.w;
    *(float4*)(out_q + (size_t)p * DIM + t * 4) = o;
    float ls = d.x * d.x + d.y * d.y + d.z * d.z + d.w * d.w;
#pragma unroll
    for (int off = 32; off > 0; off >>= 1) ls += __shfl_down(ls, off, 64);
    __shared__ float red[2];
    if ((t & 63) == 0) red[t >> 6] = ls;
    __syncthreads();
    if (t == 0) {
        psums[p] = red[0] + red[1];
        out_idx[p] = (float)bi;
        atomicAdd(&counts[bi], 1u);
    }
}

// ================================================================ launch
extern "C" void kernel_launch(void* const* d_in, const int* in_sizes, int n_in,
                              void* d_out, int out_size, void* d_ws, size_t ws_size,
                              hipStream_t stream) {
    const float* z_e = (const float*)d_in[0];
    const float* cb  = (const float*)d_in[1];
    float* out = (float*)d_out;
    char* ws = (char*)d_ws;

    if (ws_size >= WS_NEED) {
        _Float16* A3      = (_Float16*)(ws + OFF_A3);
        _Float16* B3      = (_Float16*)(ws + OFF_B3);
        float* cnorm      = (float*)(ws + OFF_CN);
        float* pv1        = (float*)(ws + OFF_PV1);
        int* pi1          = (int*)(ws + OFF_PI1);
        float* pv2        = (float*)(ws + OFF_PV2);
        int* pi2          = (int*)(ws + OFF_PI2);
        float* psums      = (float*)(ws + OFF_PSUM);
        unsigned int* cnt = (unsigned int*)(ws + OFF_CNT);

        prep_all<<<1024, 256, 0, stream>>>(z_e, cb, A3, B3, cnorm, cnt, psums);
        dim3 g(N_PTS / 128, NSPLIT);                   // 128 x 16 blocks
        score_kernel<<<g, 256, 0, stream>>>(A3, B3, cnorm, pv1, pi1, pv2, pi2);
        gather_kernel<<<N_PTS / 4, 256, 0, stream>>>(z_e, cb, pv1, pi1, pv2, pi2,
                                                     out, out + OUT0_N, cnt, psums);
        finalize_kernel<<<1, 256, 0, stream>>>(cnt, psums, out + OUT0_N + N_PTS);
    } else {
        // round-1 fp32 fallback (<700 KB ws)
        float* cnorm      = (float*)ws;
        float* pmin       = (float*)(ws + 32768);
        int* pidx         = (int*)(ws + 32768 + 262144);
        unsigned int* cnt = (unsigned int*)(ws + 32768 + 2 * 262144);
        float* psums      = (float*)(ws + 32768 + 2 * 262144 + 32768);

        hipMemsetAsync(cnt, 0, 32768, stream);
        cnorm_kernel<<<K_CODES, 128, 0, stream>>>(cb, cnorm);
        dim3 grid1(N_PTS / FB_MT, FB_SPLIT);
        fb_dist_argmin_kernel<<<grid1, 256, 0, stream>>>(z_e, cb, cnorm, pmin, pidx);
        fb_gather_kernel<<<N_PTS, 128, 0, stream>>>(z_e, cb, pmin, pidx,
                                                    out, out + OUT0_N, cnt, psums);
        finalize_kernel<<<1, 256, 0, stream>>>(cnt, psums, out + OUT0_N + N_PTS);
    }
}